// Round 5
// baseline (46.366 us; speedup 1.0000x reference)
//
#include <hip/hip_runtime.h>

// LSTM_8589935226: B=4194304 independent LSTMs, T=4, I=1, H=2, C=1.
// Round 5: ILP=4 — four independent LSTM chains per thread, interleaved at
// step granularity so the scheduler fills trans/dependency stalls with the
// sibling chains' work. (R4 showed VALUBusy 70%: issue port 30% idle.)
// Model: per-wave issue cyc = 2V + 17T; ILP=4 at ~95% busy -> ~35 us.

__device__ __forceinline__ float fexp2(float x) { return __builtin_amdgcn_exp2f(x); }
__device__ __forceinline__ float frcp(float x)  { return __builtin_amdgcn_rcpf(x); }

#define S2C 2.8853900817779268f   // 2*log2(e)

// ws layout: [0..7]=wi, [8..15]=wh0, [16..23]=wh1, [24..31]=bb, [32]=wf0,
// [33]=wf1, [34]=bf
__global__ void lstm_prep(const float* __restrict__ W_ih,
                          const float* __restrict__ W_hh,
                          const float* __restrict__ b_ih,
                          const float* __restrict__ b_hh,
                          const float* __restrict__ W_fc,
                          const float* __restrict__ b_fc,
                          float* __restrict__ ws)
{
    const int k = threadIdx.x;
    if (k < 8) {
        const float L2E = 1.4426950408889634f;
        // gate order i(0,1) f(2,3) g(4,5) o(6,7); sigmoid rows * -log2e,
        // tanh(g) rows * +2*log2e
        const float s = (k == 4 || k == 5) ? S2C : -L2E;
        ws[k]      = W_ih[k] * s;
        ws[8 + k]  = W_hh[2 * k] * s;
        ws[16 + k] = W_hh[2 * k + 1] * s;
        ws[24 + k] = (b_ih[k] + b_hh[k]) * s;
    } else if (k == 8) {
        ws[32] = W_fc[0];
        ws[33] = W_fc[1];
        ws[34] = b_fc[0];
    }
}

// One timestep t>=1 for one chain. State passed by reference.
__device__ __forceinline__ void lstm_step(float xt,
                                          float& h0, float& h1,
                                          float& c0, float& c1,
                                          const float* __restrict__ wi,
                                          const float* __restrict__ wh0,
                                          const float* __restrict__ wh1,
                                          const float* __restrict__ bb)
{
    float pr[8];
#pragma unroll
    for (int k = 0; k < 8; ++k)
        pr[k] = fmaf(xt, wi[k], fmaf(h0, wh0[k], fmaf(h1, wh1[k], bb[k])));
    const float e0 = fexp2(pr[0]), e1 = fexp2(pr[1]);
    const float e2 = fexp2(pr[2]), e3 = fexp2(pr[3]);
    const float e4 = fexp2(pr[4]), e5 = fexp2(pr[5]);
    const float e6 = fexp2(pr[6]), e7 = fexp2(pr[7]);
    const float di0 = 1.f + e0, di1 = 1.f + e1;
    const float df0 = 1.f + e2, df1 = 1.f + e3;
    const float dg0 = 1.f + e4, dg1 = 1.f + e5;
    const float do0 = 1.f + e6, do1 = 1.f + e7;
    const float m0 = di0 * dg0, m1 = di1 * dg1;
    // Montgomery-6 over {m0, df0, do0, m1, df1, do1}: one rcp
    const float P1 = m0 * df0, P2 = P1 * do0, P3 = P2 * m1,
                P4 = P3 * df1, P5 = P4 * do1;
    float R = frcp(P5);
    const float vDo1 = R * P4;  R *= do1;
    const float vDf1 = R * P3;  R *= df1;
    const float vM1  = R * P2;  R *= m1;
    const float vDo0 = R * P1;  R *= do0;
    const float vDf0 = R * m0;  R *= df0;
    const float vM0  = R;
    const float ng0 = fmaf(e4, S2C, -S2C);
    const float ng1 = fmaf(e5, S2C, -S2C);
    c0 = fmaf(vDf0, c0, ng0 * vM0);
    c1 = fmaf(vDf1, c1, ng1 * vM1);
    const float ec0 = fexp2(c0), ec1 = fexp2(c1);
    const float tn0 = ec0 - 1.f, tn1 = ec1 - 1.f;
    const float td0 = ec0 + 1.f, td1 = ec1 + 1.f;
    const float Rt = frcp(td0 * td1);
    h0 = vDo0 * (tn0 * (Rt * td1));
    h1 = vDo1 * (tn1 * (Rt * td0));
}

// t = 0 (h=c=0): forget gate dead, gates affine in x0.
__device__ __forceinline__ void lstm_t0(float x0,
                                        float& h0, float& h1,
                                        float& c0, float& c1,
                                        const float* __restrict__ wi,
                                        const float* __restrict__ bb)
{
    const float pi0 = fmaf(x0, wi[0], bb[0]);
    const float pi1 = fmaf(x0, wi[1], bb[1]);
    const float pg0 = fmaf(x0, wi[4], bb[4]);
    const float pg1 = fmaf(x0, wi[5], bb[5]);
    const float po0 = fmaf(x0, wi[6], bb[6]);
    const float po1 = fmaf(x0, wi[7], bb[7]);
    const float ei0 = fexp2(pi0), ei1 = fexp2(pi1);
    const float eg0 = fexp2(pg0), eg1 = fexp2(pg1);
    const float eo0 = fexp2(po0), eo1 = fexp2(po1);
    const float di0 = 1.f + ei0, di1 = 1.f + ei1;
    const float dg0 = 1.f + eg0, dg1 = 1.f + eg1;
    const float do0 = 1.f + eo0, do1 = 1.f + eo1;
    const float m0 = di0 * dg0, m1 = di1 * dg1;
    // Montgomery-4 over {m0, do0, m1, do1}
    const float P1 = m0 * do0, P2 = P1 * m1, P3 = P2 * do1;
    float R = frcp(P3);
    const float vDo1 = R * P2;  R *= do1;
    const float vM1  = R * P1;  R *= m1;
    const float vDo0 = R * m0;  R *= do0;
    const float vM0  = R;
    const float ng0 = fmaf(eg0, S2C, -S2C);
    const float ng1 = fmaf(eg1, S2C, -S2C);
    c0 = ng0 * vM0;
    c1 = ng1 * vM1;
    const float ec0 = fexp2(c0), ec1 = fexp2(c1);
    const float tn0 = ec0 - 1.f, tn1 = ec1 - 1.f;
    const float td0 = ec0 + 1.f, td1 = ec1 + 1.f;
    const float Rt = frcp(td0 * td1);
    h0 = vDo0 * (tn0 * (Rt * td1));
    h1 = vDo1 * (tn1 * (Rt * td0));
}

__global__ __launch_bounds__(256) void lstm_main(
    const float4* __restrict__ x,   // [B] float4 per element
    const float*  __restrict__ ws,  // preprocessed constants
    float4* __restrict__ out,       // [B/4]
    int B4)                         // B/4
{
    const int idx = blockIdx.x * blockDim.x + threadIdx.x;
    if (idx >= B4) return;

    const float* wi  = ws;
    const float* wh0 = ws + 8;
    const float* wh1 = ws + 16;
    const float* bb  = ws + 24;
    const float wf0 = ws[32], wf1 = ws[33], bf = ws[34];

    // Load 4 elements (64 contiguous bytes per thread).
    float4 xv[4];
#pragma unroll
    for (int e = 0; e < 4; ++e) xv[e] = x[4 * idx + e];
    float xx[4][4];
#pragma unroll
    for (int e = 0; e < 4; ++e) {
        xx[e][0] = xv[e].x; xx[e][1] = xv[e].y;
        xx[e][2] = xv[e].z; xx[e][3] = xv[e].w;
    }

    float h0[4], h1[4], c0[4], c1[4];

    // t=0, all chains adjacent -> scheduler interleaves the 4 chains
#pragma unroll
    for (int e = 0; e < 4; ++e)
        lstm_t0(xx[e][0], h0[e], h1[e], c0[e], c1[e], wi, bb);

    // t=1..3, step-granularity interleave
#pragma unroll
    for (int t = 1; t < 4; ++t) {
#pragma unroll
        for (int e = 0; e < 4; ++e)
            lstm_step(xx[e][t], h0[e], h1[e], c0[e], c1[e], wi, wh0, wh1, bb);
    }

    float4 o;
    o.x = fmaf(h0[0], wf0, fmaf(h1[0], wf1, bf));
    o.y = fmaf(h0[1], wf0, fmaf(h1[1], wf1, bf));
    o.z = fmaf(h0[2], wf0, fmaf(h1[2], wf1, bf));
    o.w = fmaf(h0[3], wf0, fmaf(h1[3], wf1, bf));
    out[idx] = o;
}

extern "C" void kernel_launch(void* const* d_in, const int* in_sizes, int n_in,
                              void* d_out, int out_size, void* d_ws, size_t ws_size,
                              hipStream_t stream)
{
    const float*  W_ih = (const float*)d_in[1];
    const float*  W_hh = (const float*)d_in[2];
    const float*  b_ih = (const float*)d_in[3];
    const float*  b_hh = (const float*)d_in[4];
    const float*  W_fc = (const float*)d_in[5];
    const float*  b_fc = (const float*)d_in[6];
    float* ws = (float*)d_ws;

    lstm_prep<<<1, 64, 0, stream>>>(W_ih, W_hh, b_ih, b_hh, W_fc, b_fc, ws);

    const float4* x = (const float4*)d_in[0];
    float4* out = (float4*)d_out;
    const int B = in_sizes[0] / 4;
    const int B4 = B / 4;
    const int threads = 256;
    const int blocks = (B4 + threads - 1) / threads;
    lstm_main<<<blocks, threads, 0, stream>>>(x, ws, out, B4);
}

// Round 6
// 46.207 us; speedup vs baseline: 1.0034x; 1.0034x over previous
//
#include <hip/hip_runtime.h>

// LSTM_8589935226: B=4194304 independent LSTMs, T=4, I=1, H=2, C=1.
// Round 6: R4 arithmetic (exp2 + Montgomery, ILP=2) + pipelined grid-stride:
// 4 iterations x 2 elems/thread, next iteration's x-loads issued before the
// current iteration's compute (register double-buffer) so first-use HBM
// latency (~900 cyc) is exposed only once per thread, not once per iteration.
// Grid = 2048 blocks = exactly 8 WGs/CU resident.
// Discriminates: issue-model b=16 (predict ~37us) vs latency-overhead model
// b=10,O~600 (predict ~30us).

__device__ __forceinline__ float fexp2(float x) { return __builtin_amdgcn_exp2f(x); }
__device__ __forceinline__ float frcp(float x)  { return __builtin_amdgcn_rcpf(x); }

#define S2C 2.8853900817779268f   // 2*log2(e)
#define ITERS 4

// ws layout: [0..7]=wi, [8..15]=wh0, [16..23]=wh1, [24..31]=bb, [32]=wf0,
// [33]=wf1, [34]=bf
__global__ void lstm_prep(const float* __restrict__ W_ih,
                          const float* __restrict__ W_hh,
                          const float* __restrict__ b_ih,
                          const float* __restrict__ b_hh,
                          const float* __restrict__ W_fc,
                          const float* __restrict__ b_fc,
                          float* __restrict__ ws)
{
    const int k = threadIdx.x;
    if (k < 8) {
        const float L2E = 1.4426950408889634f;
        const float s = (k == 4 || k == 5) ? S2C : -L2E;
        ws[k]      = W_ih[k] * s;
        ws[8 + k]  = W_hh[2 * k] * s;
        ws[16 + k] = W_hh[2 * k + 1] * s;
        ws[24 + k] = (b_ih[k] + b_hh[k]) * s;
    } else if (k == 8) {
        ws[32] = W_fc[0];
        ws[33] = W_fc[1];
        ws[34] = b_fc[0];
    }
}

__device__ __forceinline__ float lstm_elem(const float4 xv,
                                           const float* __restrict__ wi,
                                           const float* __restrict__ wh0,
                                           const float* __restrict__ wh1,
                                           const float* __restrict__ bb,
                                           float wf0, float wf1, float bf)
{
    float h0, h1, c0, c1;  // c in scaled domain (c' = S2C * c_true)

    // ---- t = 0: h=c=0 -> f-gate dead, gates affine in x0 ----
    {
        const float x0 = xv.x;
        const float pi0 = fmaf(x0, wi[0], bb[0]);
        const float pi1 = fmaf(x0, wi[1], bb[1]);
        const float pg0 = fmaf(x0, wi[4], bb[4]);
        const float pg1 = fmaf(x0, wi[5], bb[5]);
        const float po0 = fmaf(x0, wi[6], bb[6]);
        const float po1 = fmaf(x0, wi[7], bb[7]);
        const float ei0 = fexp2(pi0), ei1 = fexp2(pi1);
        const float eg0 = fexp2(pg0), eg1 = fexp2(pg1);
        const float eo0 = fexp2(po0), eo1 = fexp2(po1);
        const float di0 = 1.f + ei0, di1 = 1.f + ei1;
        const float dg0 = 1.f + eg0, dg1 = 1.f + eg1;
        const float do0 = 1.f + eo0, do1 = 1.f + eo1;
        const float m0 = di0 * dg0, m1 = di1 * dg1;
        const float P1 = m0 * do0, P2 = P1 * m1, P3 = P2 * do1;
        float R = frcp(P3);
        const float vDo1 = R * P2;  R *= do1;
        const float vM1  = R * P1;  R *= m1;
        const float vDo0 = R * m0;  R *= do0;
        const float vM0  = R;
        const float ng0 = fmaf(eg0, S2C, -S2C);
        const float ng1 = fmaf(eg1, S2C, -S2C);
        c0 = ng0 * vM0;
        c1 = ng1 * vM1;
        const float ec0 = fexp2(c0), ec1 = fexp2(c1);
        const float tn0 = ec0 - 1.f, tn1 = ec1 - 1.f;
        const float td0 = ec0 + 1.f, td1 = ec1 + 1.f;
        const float Rt = frcp(td0 * td1);
        h0 = vDo0 * (tn0 * (Rt * td1));
        h1 = vDo1 * (tn1 * (Rt * td0));
    }

    // ---- t = 1..3 ----
    const float xs[3] = {xv.y, xv.z, xv.w};
#pragma unroll
    for (int t = 0; t < 3; ++t) {
        const float xt = xs[t];
        float pr[8];
#pragma unroll
        for (int k = 0; k < 8; ++k)
            pr[k] = fmaf(xt, wi[k], fmaf(h0, wh0[k], fmaf(h1, wh1[k], bb[k])));
        const float e0 = fexp2(pr[0]), e1 = fexp2(pr[1]);
        const float e2 = fexp2(pr[2]), e3 = fexp2(pr[3]);
        const float e4 = fexp2(pr[4]), e5 = fexp2(pr[5]);
        const float e6 = fexp2(pr[6]), e7 = fexp2(pr[7]);
        const float di0 = 1.f + e0, di1 = 1.f + e1;
        const float df0 = 1.f + e2, df1 = 1.f + e3;
        const float dg0 = 1.f + e4, dg1 = 1.f + e5;
        const float do0 = 1.f + e6, do1 = 1.f + e7;
        const float m0 = di0 * dg0, m1 = di1 * dg1;
        // Montgomery-6 over {m0, df0, do0, m1, df1, do1}: one rcp
        const float P1 = m0 * df0, P2 = P1 * do0, P3 = P2 * m1,
                    P4 = P3 * df1, P5 = P4 * do1;
        float R = frcp(P5);
        const float vDo1 = R * P4;  R *= do1;
        const float vDf1 = R * P3;  R *= df1;
        const float vM1  = R * P2;  R *= m1;
        const float vDo0 = R * P1;  R *= do0;
        const float vDf0 = R * m0;  R *= df0;
        const float vM0  = R;
        const float ng0 = fmaf(e4, S2C, -S2C);
        const float ng1 = fmaf(e5, S2C, -S2C);
        c0 = fmaf(vDf0, c0, ng0 * vM0);
        c1 = fmaf(vDf1, c1, ng1 * vM1);
        const float ec0 = fexp2(c0), ec1 = fexp2(c1);
        const float tn0 = ec0 - 1.f, tn1 = ec1 - 1.f;
        const float td0 = ec0 + 1.f, td1 = ec1 + 1.f;
        const float Rt = frcp(td0 * td1);
        h0 = vDo0 * (tn0 * (Rt * td1));
        h1 = vDo1 * (tn1 * (Rt * td0));
    }

    return fmaf(h0, wf0, fmaf(h1, wf1, bf));
}

__global__ __launch_bounds__(256, 8) void lstm_main(
    const float4* __restrict__ x,   // [B] float4 per element
    const float*  __restrict__ ws,  // preprocessed constants
    float2* __restrict__ out,       // [B/2] pairs
    int nThreads)                   // total threads = B / (2*ITERS)
{
    const int tid = blockIdx.x * blockDim.x + threadIdx.x;

    const float* wi  = ws;
    const float* wh0 = ws + 8;
    const float* wh1 = ws + 16;
    const float* bb  = ws + 24;
    const float wf0 = ws[32], wf1 = ws[33], bf = ws[34];

    // Prefetch iteration 0 (pair p = tid).
    float4 xa = x[2 * tid];
    float4 xb = x[2 * tid + 1];

#pragma unroll
    for (int it = 0; it < ITERS; ++it) {
        const int p = it * nThreads + tid;
        float4 na, nb;
        if (it + 1 < ITERS) {   // compile-time resolved (full unroll)
            const int q = p + nThreads;
            na = x[2 * q];
            nb = x[2 * q + 1];
        }
        const float oa = lstm_elem(xa, wi, wh0, wh1, bb, wf0, wf1, bf);
        const float ob = lstm_elem(xb, wi, wh0, wh1, bb, wf0, wf1, bf);
        float2 o; o.x = oa; o.y = ob;
        out[p] = o;
        if (it + 1 < ITERS) { xa = na; xb = nb; }
    }
}

extern "C" void kernel_launch(void* const* d_in, const int* in_sizes, int n_in,
                              void* d_out, int out_size, void* d_ws, size_t ws_size,
                              hipStream_t stream)
{
    const float*  W_ih = (const float*)d_in[1];
    const float*  W_hh = (const float*)d_in[2];
    const float*  b_ih = (const float*)d_in[3];
    const float*  b_hh = (const float*)d_in[4];
    const float*  W_fc = (const float*)d_in[5];
    const float*  b_fc = (const float*)d_in[6];
    float* ws = (float*)d_ws;

    lstm_prep<<<1, 64, 0, stream>>>(W_ih, W_hh, b_ih, b_hh, W_fc, b_fc, ws);

    const float4* x = (const float4*)d_in[0];
    float2* out = (float2*)d_out;
    const int B = in_sizes[0] / 4;          // 4194304
    const int nThreads = B / (2 * ITERS);   // 524288
    const int threads = 256;
    const int blocks = nThreads / threads;  // 2048 = 8 WGs/CU
    lstm_main<<<blocks, threads, 0, stream>>>(x, ws, out, nThreads);
}